// Round 2
// baseline (778.899 us; speedup 1.0000x reference)
//
#include <hip/hip_runtime.h>

typedef float f32x4 __attribute__((ext_vector_type(4)));

#define NEG_SLOPE 0.2f
#define NEG_INF   -1e9f

// ---------------------------------------------------------------------------
// Kernel 1: node embedding  h[1+n,:] = tf[n,:] @ W_emb + b_emb ; zero rows
// ---------------------------------------------------------------------------
__global__ void embed_kernel(const float* __restrict__ tf,
                             const float* __restrict__ W_emb,
                             const float* __restrict__ b_emb,
                             float* __restrict__ h_a,
                             float* __restrict__ h_b, int N) {
    int n = blockIdx.x * blockDim.x + threadIdx.x;
    if (n >= N) return;
    if (n == 0) {
        #pragma unroll
        for (int j = 0; j < 8; ++j) { h_a[j] = 0.f; h_b[j] = 0.f; }
    }
    const f32x4* tfr = reinterpret_cast<const f32x4*>(tf + (size_t)n * 8);
    f32x4 a = tfr[0], b = tfr[1];
    float x[8] = {a[0], a[1], a[2], a[3], b[0], b[1], b[2], b[3]};
    float out[8];
    #pragma unroll
    for (int j = 0; j < 8; ++j) out[j] = b_emb[j];
    #pragma unroll
    for (int i = 0; i < 8; ++i)
        #pragma unroll
        for (int j = 0; j < 8; ++j)
            out[j] += x[i] * W_emb[i * 8 + j];
    f32x4* hr = reinterpret_cast<f32x4*>(h_a + (size_t)(n + 1) * 8);
    f32x4 o0 = {out[0], out[1], out[2], out[3]};
    f32x4 o1 = {out[4], out[5], out[6], out[7]};
    hr[0] = o0;
    hr[1] = o1;
}

// ---------------------------------------------------------------------------
// Kernel 2: one GAT iteration. Grid-stride persistent blocks, 32 lanes/node,
// 2-deep software pipeline (index loads one iteration ahead).
// ITER==1: msg computed on-the-fly from fdg/rij @ W_dist (NT loads).
// ITER==2: msg row = h_cur[edge_src[b_scope-1]] (NT on edge_src).
// ---------------------------------------------------------------------------
template <int ITER>
__global__ void gat_iter_kernel(const float* __restrict__ h_cur,
                                float* __restrict__ h_next,
                                const int* __restrict__ b_scope,
                                const int* __restrict__ start_end_env,
                                const float* __restrict__ fdg,
                                const float* __restrict__ rij,
                                const int* __restrict__ edge_src,
                                const float* __restrict__ W_dist,
                                const float* __restrict__ b_dist,
                                const float* __restrict__ W_gat,
                                const float* __restrict__ a_src,
                                const float* __restrict__ a_dst,
                                int N, int K) {
    __shared__ float sWg[64];   // W_gat
    __shared__ float sWd[72];   // W_dist (iter 1 only)
    __shared__ float sbd[8];    // b_dist
    __shared__ float s_as[8];   // W_gat @ a_src
    __shared__ float s_ad[8];   // W_gat @ a_dst

    int tid = threadIdx.x;
    if (tid < 64) sWg[tid] = W_gat[tid];
    if (ITER == 1) {
        if (tid >= 64 && tid < 136) sWd[tid - 64] = W_dist[tid - 64];
        if (tid >= 136 && tid < 144) sbd[tid - 136] = b_dist[tid - 136];
    }
    __syncthreads();
    if (tid < 8) {
        float s = 0.f;
        #pragma unroll
        for (int j = 0; j < 8; ++j) s += sWg[tid * 8 + j] * a_src[j];
        s_as[tid] = s;
    } else if (tid < 16) {
        int i = tid - 8;
        float s = 0.f;
        #pragma unroll
        for (int j = 0; j < 8; ++j) s += sWg[i * 8 + j] * a_dst[j];
        s_ad[i] = s;
    }
    __syncthreads();

    const int lane = tid & 31;            // neighbor slot k
    const int grp  = tid >> 5;            // 0..7 node-groups per block
    const bool vk  = (lane < K);
    const int nstep = gridDim.x * 8;

    int node = blockIdx.x * 8 + grp;
    if (node >= N) return;

    // prologue: indices for first node
    int bs = 0, se = 0;
    if (vk) {
        bs = __builtin_nontemporal_load(b_scope + (size_t)node * K + lane);
        se = __builtin_nontemporal_load(start_end_env + (size_t)node * K + lane);
    }

    for (; node < N; node += nstep) {
        // ---- issue gathers for current node ----
        f32x4 hse0 = {0.f, 0.f, 0.f, 0.f}, hse1 = {0.f, 0.f, 0.f, 0.f};
        if (vk) {
            const f32x4* hr = reinterpret_cast<const f32x4*>(h_cur + (size_t)se * 8);
            hse0 = hr[0];
            hse1 = hr[1];
        }
        bool has = vk && (bs > 0);
        f32x4 g0 = {0.f, 0.f, 0.f, 0.f}, g1 = {0.f, 0.f, 0.f, 0.f};
        float rv = 0.f;
        int src = 0;
        if (ITER == 1) {
            if (has) {
                const f32x4* fr = reinterpret_cast<const f32x4*>(fdg + (size_t)(bs - 1) * 8);
                g0 = __builtin_nontemporal_load(fr);
                g1 = __builtin_nontemporal_load(fr + 1);
                rv = __builtin_nontemporal_load(rij + (bs - 1));
            }
        } else {
            if (has) src = __builtin_nontemporal_load(edge_src + (bs - 1));
        }

        // ---- prefetch next node's indices (pipeline stage) ----
        int nn = node + nstep;
        int bs2 = 0, se2 = 0;
        if (nn < N && vk) {
            bs2 = __builtin_nontemporal_load(b_scope + (size_t)nn * K + lane);
            se2 = __builtin_nontemporal_load(start_end_env + (size_t)nn * K + lane);
        }

        // ---- compute current node ----
        float msg[8];
        #pragma unroll
        for (int j = 0; j < 8; ++j) msg[j] = 0.f;
        if (ITER == 1) {
            if (has) {
                #pragma unroll
                for (int j = 0; j < 8; ++j) {
                    float s = sbd[j];
                    #pragma unroll
                    for (int i = 0; i < 4; ++i) s += g0[i] * sWd[i * 8 + j];
                    #pragma unroll
                    for (int i = 0; i < 4; ++i) s += g1[i] * sWd[(4 + i) * 8 + j];
                    s += rv * sWd[64 + j];
                    msg[j] = s;
                }
            }
        } else {
            if (has) {
                const f32x4* mr = reinterpret_cast<const f32x4*>(h_cur + (size_t)src * 8);
                f32x4 m0 = mr[0], m1 = mr[1];
                msg[0] = m0[0]; msg[1] = m0[1]; msg[2] = m0[2]; msg[3] = m0[3];
                msg[4] = m1[0]; msg[5] = m1[1]; msg[6] = m1[2]; msg[7] = m1[3];
            }
        }

        float s_s = hse0[0] * s_as[0] + hse0[1] * s_as[1] + hse0[2] * s_as[2] + hse0[3] * s_as[3]
                  + hse1[0] * s_as[4] + hse1[1] * s_as[5] + hse1[2] * s_as[6] + hse1[3] * s_as[7];
        float s_m = 0.f;
        #pragma unroll
        for (int j = 0; j < 8; ++j) s_m += msg[j] * s_ad[j];
        float ee = s_s + s_m;
        ee = (ee >= 0.f) ? ee : NEG_SLOPE * ee;            // leaky relu
        float e = has ? ee : (vk ? NEG_INF : -3e38f);      // pad mask / lane mask

        // softmax over the 32-lane group
        float m = e;
        #pragma unroll
        for (int off = 16; off; off >>= 1) m = fmaxf(m, __shfl_xor(m, off, 32));
        float p = vk ? expf(e - m) : 0.f;
        float denom = p;
        #pragma unroll
        for (int off = 16; off; off >>= 1) denom += __shfl_xor(denom, off, 32);
        float alpha = p / denom;

        // weighted aggregate of msg rows (8-wide butterfly)
        float agg[8];
        #pragma unroll
        for (int j = 0; j < 8; ++j) agg[j] = alpha * msg[j];
        #pragma unroll
        for (int off = 16; off; off >>= 1)
            #pragma unroll
            for (int j = 0; j < 8; ++j) agg[j] += __shfl_xor(agg[j], off, 32);

        // lanes 0..7: out_j = (agg @ W_gat)_j, then ELU, store
        if (lane < 8) {
            float o = 0.f;
            #pragma unroll
            for (int i = 0; i < 8; ++i) o += agg[i] * sWg[i * 8 + lane];
            o = (o > 0.f) ? o : (expf(o) - 1.f);           // elu
            h_next[(size_t)(node + 1) * 8 + lane] = o;
        }

        // rotate pipeline
        bs = bs2;
        se = se2;
    }
}

// ---------------------------------------------------------------------------
// Kernel 3: readout  out[b,:] = sum_l h[l_scope[b,l], :]
// ---------------------------------------------------------------------------
__global__ void readout_kernel(const float* __restrict__ h,
                               const int* __restrict__ l_scope,
                               float* __restrict__ out, int B, int L) {
    int gid = blockIdx.x * blockDim.x + threadIdx.x;
    int b = gid >> 3;
    int j = gid & 7;
    if (b >= B) return;
    float s = 0.f;
    for (int l = 0; l < L; ++l) {
        int idx = l_scope[(size_t)b * L + l];
        s += h[(size_t)idx * 8 + j];
    }
    out[(size_t)b * 8 + j] = s;
}

// ---------------------------------------------------------------------------
extern "C" void kernel_launch(void* const* d_in, const int* in_sizes, int n_in,
                              void* d_out, int out_size, void* d_ws, size_t ws_size,
                              hipStream_t stream) {
    const float* tf      = (const float*)d_in[0];
    const float* fdg     = (const float*)d_in[1];
    const float* rij     = (const float*)d_in[2];
    const int* b_scope   = (const int*)d_in[3];
    const int* start_env = (const int*)d_in[4];
    const int* l_scope   = (const int*)d_in[5];
    const int* edge_src  = (const int*)d_in[6];
    const float* W_emb   = (const float*)d_in[7];
    const float* b_emb   = (const float*)d_in[8];
    const float* W_dist  = (const float*)d_in[9];
    const float* b_dist  = (const float*)d_in[10];
    const float* W_gat   = (const float*)d_in[11];
    const float* a_src   = (const float*)d_in[12];
    const float* a_dst   = (const float*)d_in[13];
    float* out = (float*)d_out;

    const int N = in_sizes[0] / 8;          // 204800
    const int K = in_sizes[3] / N;          // 30
    const int L = 50;
    const int B = in_sizes[5] / L;          // 4096

    float* h_a = (float*)d_ws;              // (N+1)*8 floats
    float* h_b = h_a + (size_t)(N + 1) * 8; // (N+1)*8 floats

    embed_kernel<<<(N + 255) / 256, 256, 0, stream>>>(tf, W_emb, b_emb, h_a, h_b, N);

    const int gat_blocks = 2048;
    gat_iter_kernel<1><<<gat_blocks, 256, 0, stream>>>(h_a, h_b, b_scope, start_env,
                                                       fdg, rij, edge_src,
                                                       W_dist, b_dist, W_gat, a_src, a_dst, N, K);
    gat_iter_kernel<2><<<gat_blocks, 256, 0, stream>>>(h_b, h_a, b_scope, start_env,
                                                       fdg, rij, edge_src,
                                                       W_dist, b_dist, W_gat, a_src, a_dst, N, K);

    readout_kernel<<<(B * 8 + 255) / 256, 256, 0, stream>>>(h_a, l_scope, out, B, L);
}

// Round 3
// 587.159 us; speedup vs baseline: 1.3266x; 1.3266x over previous
//
#include <hip/hip_runtime.h>

typedef float f32x4 __attribute__((ext_vector_type(4)));

#define NEG_SLOPE 0.2f
#define NEG_INF   -1e9f

// ---------------------------------------------------------------------------
// Kernel 1: node embedding  h[1+n,:] = tf[n,:] @ W_emb + b_emb ; zero rows
// ---------------------------------------------------------------------------
__global__ void embed_kernel(const float* __restrict__ tf,
                             const float* __restrict__ W_emb,
                             const float* __restrict__ b_emb,
                             float* __restrict__ h_a,
                             float* __restrict__ h_b, int N) {
    int n = blockIdx.x * blockDim.x + threadIdx.x;
    if (n >= N) return;
    if (n == 0) {
        #pragma unroll
        for (int j = 0; j < 8; ++j) { h_a[j] = 0.f; h_b[j] = 0.f; }
    }
    const f32x4* tfr = reinterpret_cast<const f32x4*>(tf + (size_t)n * 8);
    f32x4 a = tfr[0], b = tfr[1];
    float x[8] = {a[0], a[1], a[2], a[3], b[0], b[1], b[2], b[3]};
    float out[8];
    #pragma unroll
    for (int j = 0; j < 8; ++j) out[j] = b_emb[j];
    #pragma unroll
    for (int i = 0; i < 8; ++i)
        #pragma unroll
        for (int j = 0; j < 8; ++j)
            out[j] += x[i] * W_emb[i * 8 + j];
    f32x4* hr = reinterpret_cast<f32x4*>(h_a + (size_t)(n + 1) * 8);
    f32x4 o0 = {out[0], out[1], out[2], out[3]};
    f32x4 o1 = {out[4], out[5], out[6], out[7]};
    hr[0] = o0;
    hr[1] = o1;
}

// ---------------------------------------------------------------------------
// Shared per-node compute: attention logit -> softmax -> aggregate -> store
// ---------------------------------------------------------------------------
__device__ __forceinline__ void gat_finish(const float msg[8], float s_s,
                                           bool has, bool vk, int lane, int node,
                                           const float* __restrict__ s_ad,
                                           const float* __restrict__ sWg,
                                           float* __restrict__ h_next) {
    float s_m = 0.f;
    #pragma unroll
    for (int j = 0; j < 8; ++j) s_m += msg[j] * s_ad[j];
    float ee = s_s + s_m;
    ee = (ee >= 0.f) ? ee : NEG_SLOPE * ee;            // leaky relu
    float e = has ? ee : (vk ? NEG_INF : -3e38f);      // pad mask / lane mask

    // softmax over the 32-lane group
    float m = e;
    #pragma unroll
    for (int off = 16; off; off >>= 1) m = fmaxf(m, __shfl_xor(m, off, 32));
    float p = vk ? expf(e - m) : 0.f;
    float denom = p;
    #pragma unroll
    for (int off = 16; off; off >>= 1) denom += __shfl_xor(denom, off, 32);
    float alpha = p / denom;

    // weighted aggregate of msg rows (8-wide butterfly)
    float agg[8];
    #pragma unroll
    for (int j = 0; j < 8; ++j) agg[j] = alpha * msg[j];
    #pragma unroll
    for (int off = 16; off; off >>= 1)
        #pragma unroll
        for (int j = 0; j < 8; ++j) agg[j] += __shfl_xor(agg[j], off, 32);

    // lanes 0..7: out_j = (agg @ W_gat)_j, then ELU, store
    if (lane < 8) {
        float o = 0.f;
        #pragma unroll
        for (int i = 0; i < 8; ++i) o += agg[i] * sWg[i * 8 + lane];
        o = (o > 0.f) ? o : (expf(o) - 1.f);           // elu
        h_next[(size_t)(node + 1) * 8 + lane] = o;
    }
}

// ---------------------------------------------------------------------------
// Kernel 2: one GAT iteration. Each 32-lane group handles TWO nodes; all
// random gathers for both nodes are issued before either node's compute so
// two gather chains are in flight per lane (2x memory-level parallelism).
// ITER==1: msg computed on-the-fly from fdg/rij @ W_dist.
// ITER==2: msg row = h_cur[edge_src[b_scope-1]].
// ---------------------------------------------------------------------------
template <int ITER>
__global__ void gat_iter_kernel(const float* __restrict__ h_cur,
                                float* __restrict__ h_next,
                                const int* __restrict__ b_scope,
                                const int* __restrict__ start_end_env,
                                const float* __restrict__ fdg,
                                const float* __restrict__ rij,
                                const int* __restrict__ edge_src,
                                const float* __restrict__ W_dist,
                                const float* __restrict__ b_dist,
                                const float* __restrict__ W_gat,
                                const float* __restrict__ a_src,
                                const float* __restrict__ a_dst,
                                int N, int K) {
    __shared__ float sWg[64];   // W_gat
    __shared__ float sWd[72];   // W_dist (iter 1 only)
    __shared__ float sbd[8];    // b_dist
    __shared__ float s_as[8];   // W_gat @ a_src
    __shared__ float s_ad[8];   // W_gat @ a_dst

    int tid = threadIdx.x;
    if (tid < 64) sWg[tid] = W_gat[tid];
    if (ITER == 1) {
        if (tid >= 64 && tid < 136) sWd[tid - 64] = W_dist[tid - 64];
        if (tid >= 136 && tid < 144) sbd[tid - 136] = b_dist[tid - 136];
    }
    __syncthreads();
    if (tid < 8) {
        float s = 0.f;
        #pragma unroll
        for (int j = 0; j < 8; ++j) s += sWg[tid * 8 + j] * a_src[j];
        s_as[tid] = s;
    } else if (tid < 16) {
        int i = tid - 8;
        float s = 0.f;
        #pragma unroll
        for (int j = 0; j < 8; ++j) s += sWg[i * 8 + j] * a_dst[j];
        s_ad[i] = s;
    }
    __syncthreads();

    if (blockIdx.x == 0 && tid < 8) h_next[tid] = 0.f;  // zero row

    const int lane = tid & 31;            // neighbor slot k
    const int grp  = tid >> 5;            // 0..7 groups per block
    const bool vk  = (lane < K);

    int g  = blockIdx.x * 8 + grp;        // group id
    int nA = g * 2;
    int nB = g * 2 + 1;
    if (nA >= N) return;
    bool hasB_node = (nB < N);

    // ---- index loads (coalesced) for both nodes ----
    int bsA = 0, seA = 0, bsB = 0, seB = 0;
    if (vk) {
        bsA = b_scope[(size_t)nA * K + lane];
        seA = start_end_env[(size_t)nA * K + lane];
        if (hasB_node) {
            bsB = b_scope[(size_t)nB * K + lane];
            seB = start_end_env[(size_t)nB * K + lane];
        }
    }
    bool hasA = vk && (bsA > 0);
    bool hasB = vk && hasB_node && (bsB > 0);

    // ---- issue ALL random gathers for both nodes ----
    f32x4 hA0 = {0,0,0,0}, hA1 = {0,0,0,0}, hB0 = {0,0,0,0}, hB1 = {0,0,0,0};
    if (vk) {
        const f32x4* hr = reinterpret_cast<const f32x4*>(h_cur + (size_t)seA * 8);
        hA0 = hr[0]; hA1 = hr[1];
        if (hasB_node) {
            const f32x4* hr2 = reinterpret_cast<const f32x4*>(h_cur + (size_t)seB * 8);
            hB0 = hr2[0]; hB1 = hr2[1];
        }
    }

    float msgA[8], msgB[8];
    #pragma unroll
    for (int j = 0; j < 8; ++j) { msgA[j] = 0.f; msgB[j] = 0.f; }

    if (ITER == 1) {
        f32x4 gA0 = {0,0,0,0}, gA1 = {0,0,0,0}, gB0 = {0,0,0,0}, gB1 = {0,0,0,0};
        float rvA = 0.f, rvB = 0.f;
        if (hasA) {
            const f32x4* fr = reinterpret_cast<const f32x4*>(fdg + (size_t)(bsA - 1) * 8);
            gA0 = fr[0]; gA1 = fr[1];
            rvA = rij[bsA - 1];
        }
        if (hasB) {
            const f32x4* fr = reinterpret_cast<const f32x4*>(fdg + (size_t)(bsB - 1) * 8);
            gB0 = fr[0]; gB1 = fr[1];
            rvB = rij[bsB - 1];
        }
        if (hasA) {
            #pragma unroll
            for (int j = 0; j < 8; ++j) {
                float s = sbd[j];
                #pragma unroll
                for (int i = 0; i < 4; ++i) s += gA0[i] * sWd[i * 8 + j];
                #pragma unroll
                for (int i = 0; i < 4; ++i) s += gA1[i] * sWd[(4 + i) * 8 + j];
                s += rvA * sWd[64 + j];
                msgA[j] = s;
            }
        }
        if (hasB) {
            #pragma unroll
            for (int j = 0; j < 8; ++j) {
                float s = sbd[j];
                #pragma unroll
                for (int i = 0; i < 4; ++i) s += gB0[i] * sWd[i * 8 + j];
                #pragma unroll
                for (int i = 0; i < 4; ++i) s += gB1[i] * sWd[(4 + i) * 8 + j];
                s += rvB * sWd[64 + j];
                msgB[j] = s;
            }
        }
    } else {
        // dependent chains for both nodes, interleaved
        int srcA = 0, srcB = 0;
        if (hasA) srcA = edge_src[bsA - 1];
        if (hasB) srcB = edge_src[bsB - 1];
        if (hasA) {
            const f32x4* mr = reinterpret_cast<const f32x4*>(h_cur + (size_t)srcA * 8);
            f32x4 m0 = mr[0], m1 = mr[1];
            msgA[0] = m0[0]; msgA[1] = m0[1]; msgA[2] = m0[2]; msgA[3] = m0[3];
            msgA[4] = m1[0]; msgA[5] = m1[1]; msgA[6] = m1[2]; msgA[7] = m1[3];
        }
        if (hasB) {
            const f32x4* mr = reinterpret_cast<const f32x4*>(h_cur + (size_t)srcB * 8);
            f32x4 m0 = mr[0], m1 = mr[1];
            msgB[0] = m0[0]; msgB[1] = m0[1]; msgB[2] = m0[2]; msgB[3] = m0[3];
            msgB[4] = m1[0]; msgB[5] = m1[1]; msgB[6] = m1[2]; msgB[7] = m1[3];
        }
    }

    float s_sA = hA0[0]*s_as[0] + hA0[1]*s_as[1] + hA0[2]*s_as[2] + hA0[3]*s_as[3]
               + hA1[0]*s_as[4] + hA1[1]*s_as[5] + hA1[2]*s_as[6] + hA1[3]*s_as[7];
    float s_sB = hB0[0]*s_as[0] + hB0[1]*s_as[1] + hB0[2]*s_as[2] + hB0[3]*s_as[3]
               + hB1[0]*s_as[4] + hB1[1]*s_as[5] + hB1[2]*s_as[6] + hB1[3]*s_as[7];

    gat_finish(msgA, s_sA, hasA, vk, lane, nA, s_ad, sWg, h_next);
    if (hasB_node)
        gat_finish(msgB, s_sB, hasB, vk, lane, nB, s_ad, sWg, h_next);
}

// ---------------------------------------------------------------------------
// Kernel 3: readout  out[b,:] = sum_l h[l_scope[b,l], :]
// ---------------------------------------------------------------------------
__global__ void readout_kernel(const float* __restrict__ h,
                               const int* __restrict__ l_scope,
                               float* __restrict__ out, int B, int L) {
    int gid = blockIdx.x * blockDim.x + threadIdx.x;
    int b = gid >> 3;
    int j = gid & 7;
    if (b >= B) return;
    float s = 0.f;
    for (int l = 0; l < L; ++l) {
        int idx = l_scope[(size_t)b * L + l];
        s += h[(size_t)idx * 8 + j];
    }
    out[(size_t)b * 8 + j] = s;
}

// ---------------------------------------------------------------------------
extern "C" void kernel_launch(void* const* d_in, const int* in_sizes, int n_in,
                              void* d_out, int out_size, void* d_ws, size_t ws_size,
                              hipStream_t stream) {
    const float* tf      = (const float*)d_in[0];
    const float* fdg     = (const float*)d_in[1];
    const float* rij     = (const float*)d_in[2];
    const int* b_scope   = (const int*)d_in[3];
    const int* start_env = (const int*)d_in[4];
    const int* l_scope   = (const int*)d_in[5];
    const int* edge_src  = (const int*)d_in[6];
    const float* W_emb   = (const float*)d_in[7];
    const float* b_emb   = (const float*)d_in[8];
    const float* W_dist  = (const float*)d_in[9];
    const float* b_dist  = (const float*)d_in[10];
    const float* W_gat   = (const float*)d_in[11];
    const float* a_src   = (const float*)d_in[12];
    const float* a_dst   = (const float*)d_in[13];
    float* out = (float*)d_out;

    const int N = in_sizes[0] / 8;          // 204800
    const int K = in_sizes[3] / N;          // 30
    const int L = 50;
    const int B = in_sizes[5] / L;          // 4096

    float* h_a = (float*)d_ws;              // (N+1)*8 floats
    float* h_b = h_a + (size_t)(N + 1) * 8; // (N+1)*8 floats

    embed_kernel<<<(N + 255) / 256, 256, 0, stream>>>(tf, W_emb, b_emb, h_a, h_b, N);

    // one 32-lane group per 2 nodes; 8 groups per 256-thread block
    const int ngroups = (N + 1) / 2;
    const int gat_blocks = (ngroups + 7) / 8;
    gat_iter_kernel<1><<<gat_blocks, 256, 0, stream>>>(h_a, h_b, b_scope, start_env,
                                                       fdg, rij, edge_src,
                                                       W_dist, b_dist, W_gat, a_src, a_dst, N, K);
    gat_iter_kernel<2><<<gat_blocks, 256, 0, stream>>>(h_b, h_a, b_scope, start_env,
                                                       fdg, rij, edge_src,
                                                       W_dist, b_dist, W_gat, a_src, a_dst, N, K);

    readout_kernel<<<(B * 8 + 255) / 256, 256, 0, stream>>>(h_a, l_scope, out, B, L);
}

// Round 4
// 415.963 us; speedup vs baseline: 1.8725x; 1.4116x over previous
//
#include <hip/hip_runtime.h>

typedef float f32x4 __attribute__((ext_vector_type(4)));

#define NEG_SLOPE 0.2f
#define NEG_INF   -1e9f

// ---------------------------------------------------------------------------
// Kernel 1: node embedding + t0.  h[1+n,:] = tf[n,:] @ W_emb + b_emb,
// t0[1+n] = dot(h[1+n,:], W_gat @ a_src). Zero rows for h_a, h_b, t0, t1.
// ---------------------------------------------------------------------------
__global__ void embed_kernel(const float* __restrict__ tf,
                             const float* __restrict__ W_emb,
                             const float* __restrict__ b_emb,
                             const float* __restrict__ W_gat,
                             const float* __restrict__ a_src,
                             float* __restrict__ h_a,
                             float* __restrict__ h_b,
                             float* __restrict__ t0,
                             float* __restrict__ t1, int N) {
    __shared__ float sWg[64];
    __shared__ float s_as[8];
    int tid = threadIdx.x;
    if (tid < 64) sWg[tid] = W_gat[tid];
    __syncthreads();
    if (tid < 8) {
        float s = 0.f;
        #pragma unroll
        for (int q = 0; q < 8; ++q) s += sWg[tid * 8 + q] * a_src[q];
        s_as[tid] = s;
    }
    __syncthreads();

    int n = blockIdx.x * blockDim.x + tid;
    if (n >= N) return;
    if (n == 0) {
        #pragma unroll
        for (int j = 0; j < 8; ++j) { h_a[j] = 0.f; h_b[j] = 0.f; }
        t0[0] = 0.f;
        t1[0] = 0.f;
    }
    const f32x4* tfr = reinterpret_cast<const f32x4*>(tf + (size_t)n * 8);
    f32x4 a = tfr[0], b = tfr[1];
    float x[8] = {a[0], a[1], a[2], a[3], b[0], b[1], b[2], b[3]};
    float out[8];
    #pragma unroll
    for (int j = 0; j < 8; ++j) out[j] = b_emb[j];
    #pragma unroll
    for (int i = 0; i < 8; ++i)
        #pragma unroll
        for (int j = 0; j < 8; ++j)
            out[j] += x[i] * W_emb[i * 8 + j];

    float t = 0.f;
    #pragma unroll
    for (int p = 0; p < 8; ++p) t += out[p] * s_as[p];
    t0[n + 1] = t;

    f32x4* hr = reinterpret_cast<f32x4*>(h_a + (size_t)(n + 1) * 8);
    f32x4 o0 = {out[0], out[1], out[2], out[3]};
    f32x4 o1 = {out[4], out[5], out[6], out[7]};
    hr[0] = o0;
    hr[1] = o1;
}

// ---------------------------------------------------------------------------
// Kernel 1b (records path): streaming prep over all E edges.
// rec[e] = { msg1[0..7], em = msg1 . (W_gat@a_dst), src = edge_src[e], pad }
// 64 B per edge, 64 B aligned -> one fabric request per later random gather.
// ---------------------------------------------------------------------------
__global__ void prep_records(const float* __restrict__ fdg,
                             const float* __restrict__ rij,
                             const int* __restrict__ edge_src,
                             const float* __restrict__ W_dist,
                             const float* __restrict__ b_dist,
                             const float* __restrict__ W_gat,
                             const float* __restrict__ a_dst,
                             float* __restrict__ rec, int E) {
    __shared__ float sWd[72];
    __shared__ float sbd[8];
    __shared__ float sWg[64];
    __shared__ float s_ad[8];
    int tid = threadIdx.x;
    if (tid < 72) sWd[tid] = W_dist[tid];
    else if (tid < 80) sbd[tid - 72] = b_dist[tid - 72];
    if (tid >= 128 && tid < 192) sWg[tid - 128] = W_gat[tid - 128];
    __syncthreads();
    if (tid < 8) {
        float s = 0.f;
        #pragma unroll
        for (int j = 0; j < 8; ++j) s += sWg[tid * 8 + j] * a_dst[j];
        s_ad[tid] = s;
    }
    __syncthreads();

    int e = blockIdx.x * blockDim.x + tid;
    if (e >= E) return;
    const f32x4* fr = reinterpret_cast<const f32x4*>(fdg + (size_t)e * 8);
    f32x4 g0 = fr[0], g1 = fr[1];
    float rv = rij[e];
    float msg[8];
    #pragma unroll
    for (int j = 0; j < 8; ++j) {
        float s = sbd[j];
        #pragma unroll
        for (int i = 0; i < 4; ++i) s += g0[i] * sWd[i * 8 + j];
        #pragma unroll
        for (int i = 0; i < 4; ++i) s += g1[i] * sWd[(4 + i) * 8 + j];
        s += rv * sWd[64 + j];
        msg[j] = s;
    }
    float em = 0.f;
    #pragma unroll
    for (int j = 0; j < 8; ++j) em += msg[j] * s_ad[j];
    int src = edge_src[e];

    f32x4* op = reinterpret_cast<f32x4*>(rec + (size_t)e * 16);
    f32x4 m0 = {msg[0], msg[1], msg[2], msg[3]};
    f32x4 m1 = {msg[4], msg[5], msg[6], msg[7]};
    f32x4 m2 = {em, __int_as_float(src), 0.f, 0.f};
    f32x4 m3 = {0.f, 0.f, 0.f, 0.f};
    op[0] = m0; op[1] = m1; op[2] = m2; op[3] = m3;
}

// ---------------------------------------------------------------------------
// Kernel 2: GAT iteration 1. One 32-lane group per node.
// REC: single 64 B record gather per valid slot; t0 gather is L2-resident.
// !REC (fallback): direct fdg/rij/edge_src gathers.
// Writes h1, t1 and src_idx (edge_src[b_scope-1], -1 for pad).
// ---------------------------------------------------------------------------
template <bool REC>
__global__ void gat_iter1(const float* __restrict__ t0,
                          float* __restrict__ h1,
                          float* __restrict__ t1,
                          int* __restrict__ src_idx,
                          const int* __restrict__ b_scope,
                          const int* __restrict__ se_env,
                          const float* __restrict__ rec,
                          const float* __restrict__ fdg,
                          const float* __restrict__ rij,
                          const int* __restrict__ edge_src,
                          const float* __restrict__ W_dist,
                          const float* __restrict__ b_dist,
                          const float* __restrict__ W_gat,
                          const float* __restrict__ a_src,
                          const float* __restrict__ a_dst,
                          int N, int K) {
    __shared__ float sWg[64];
    __shared__ float s_as[8];
    __shared__ float s_ad[8];
    __shared__ float sWd[72];
    __shared__ float sbd[8];
    int tid = threadIdx.x;
    if (tid < 64) sWg[tid] = W_gat[tid];
    if (!REC) {
        if (tid >= 64 && tid < 136) sWd[tid - 64] = W_dist[tid - 64];
        if (tid >= 136 && tid < 144) sbd[tid - 136] = b_dist[tid - 136];
    }
    __syncthreads();
    if (tid < 8) {
        float s = 0.f;
        #pragma unroll
        for (int j = 0; j < 8; ++j) s += sWg[tid * 8 + j] * a_src[j];
        s_as[tid] = s;
    } else if (tid < 16) {
        int i = tid - 8;
        float s = 0.f;
        #pragma unroll
        for (int j = 0; j < 8; ++j) s += sWg[i * 8 + j] * a_dst[j];
        s_ad[i] = s;
    }
    __syncthreads();

    int node = blockIdx.x * 8 + (tid >> 5);
    int lane = tid & 31;
    if (node == 0 && lane == 0) t1[0] = 0.f;
    if (node >= N) return;
    bool vk = (lane < K);

    int bs = 0, se = 0;
    if (vk) {
        bs = b_scope[(size_t)node * K + lane];
        se = se_env[(size_t)node * K + lane];
    }
    bool has = vk && (bs > 0);
    float t_se = vk ? t0[se] : 0.f;

    float msg[8];
    #pragma unroll
    for (int j = 0; j < 8; ++j) msg[j] = 0.f;
    float em = 0.f;
    int src = -1;

    if (REC) {
        if (has) {
            const f32x4* rp = reinterpret_cast<const f32x4*>(rec + (size_t)(bs - 1) * 16);
            f32x4 m0 = rp[0], m1 = rp[1], m2 = rp[2];
            msg[0] = m0[0]; msg[1] = m0[1]; msg[2] = m0[2]; msg[3] = m0[3];
            msg[4] = m1[0]; msg[5] = m1[1]; msg[6] = m1[2]; msg[7] = m1[3];
            em = m2[0];
            src = __float_as_int(m2[1]);
        }
    } else {
        if (has) {
            const f32x4* fr = reinterpret_cast<const f32x4*>(fdg + (size_t)(bs - 1) * 8);
            f32x4 g0 = fr[0], g1 = fr[1];
            float rv = rij[bs - 1];
            src = edge_src[bs - 1];
            #pragma unroll
            for (int j = 0; j < 8; ++j) {
                float s = sbd[j];
                #pragma unroll
                for (int i = 0; i < 4; ++i) s += g0[i] * sWd[i * 8 + j];
                #pragma unroll
                for (int i = 0; i < 4; ++i) s += g1[i] * sWd[(4 + i) * 8 + j];
                s += rv * sWd[64 + j];
                msg[j] = s;
            }
            #pragma unroll
            for (int j = 0; j < 8; ++j) em += msg[j] * s_ad[j];
        }
    }

    if (vk) src_idx[(size_t)node * K + lane] = src;

    float ee = t_se + em;
    ee = (ee >= 0.f) ? ee : NEG_SLOPE * ee;            // leaky relu
    float e = has ? ee : (vk ? NEG_INF : -3e38f);      // pad / lane mask

    float m = e;
    #pragma unroll
    for (int off = 16; off; off >>= 1) m = fmaxf(m, __shfl_xor(m, off, 32));
    float p = vk ? expf(e - m) : 0.f;
    float denom = p;
    #pragma unroll
    for (int off = 16; off; off >>= 1) denom += __shfl_xor(denom, off, 32);
    float alpha = p / denom;

    float agg[8];
    #pragma unroll
    for (int j = 0; j < 8; ++j) agg[j] = alpha * msg[j];
    #pragma unroll
    for (int off = 16; off; off >>= 1)
        #pragma unroll
        for (int j = 0; j < 8; ++j) agg[j] += __shfl_xor(agg[j], off, 32);

    if (lane < 8) {
        float o = 0.f;
        #pragma unroll
        for (int i = 0; i < 8; ++i) o += agg[i] * sWg[i * 8 + lane];
        o = (o > 0.f) ? o : (expf(o) - 1.f);           // elu
        h1[(size_t)(node + 1) * 8 + lane] = o;
        float tv = o * s_as[lane];
        tv += __shfl_xor(tv, 1, 32);
        tv += __shfl_xor(tv, 2, 32);
        tv += __shfl_xor(tv, 4, 32);
        if (lane == 0) t1[node + 1] = tv;
    }
}

// ---------------------------------------------------------------------------
// Kernel 3: GAT iteration 2. src_idx read coalesced; only random gathers are
// t1[se] (L2-resident) and h1[src] (6.5 MB, partial L2).
// ---------------------------------------------------------------------------
__global__ void gat_iter2(const float* __restrict__ h1,
                          const float* __restrict__ t1,
                          float* __restrict__ h2,
                          const int* __restrict__ src_idx,
                          const int* __restrict__ se_env,
                          const float* __restrict__ W_gat,
                          const float* __restrict__ a_dst,
                          int N, int K) {
    __shared__ float sWg[64];
    __shared__ float s_ad[8];
    int tid = threadIdx.x;
    if (tid < 64) sWg[tid] = W_gat[tid];
    __syncthreads();
    if (tid < 8) {
        float s = 0.f;
        #pragma unroll
        for (int j = 0; j < 8; ++j) s += sWg[tid * 8 + j] * a_dst[j];
        s_ad[tid] = s;
    }
    __syncthreads();

    int node = blockIdx.x * 8 + (tid >> 5);
    int lane = tid & 31;
    if (node >= N) return;
    bool vk = (lane < K);

    int src = -1, se = 0;
    if (vk) {
        src = src_idx[(size_t)node * K + lane];
        se  = se_env[(size_t)node * K + lane];
    }
    bool has = vk && (src >= 0);
    float t_se = vk ? t1[se] : 0.f;

    float msg[8];
    #pragma unroll
    for (int j = 0; j < 8; ++j) msg[j] = 0.f;
    if (has) {
        const f32x4* mr = reinterpret_cast<const f32x4*>(h1 + (size_t)src * 8);
        f32x4 m0 = mr[0], m1 = mr[1];
        msg[0] = m0[0]; msg[1] = m0[1]; msg[2] = m0[2]; msg[3] = m0[3];
        msg[4] = m1[0]; msg[5] = m1[1]; msg[6] = m1[2]; msg[7] = m1[3];
    }
    float s_m = 0.f;
    #pragma unroll
    for (int j = 0; j < 8; ++j) s_m += msg[j] * s_ad[j];

    float ee = t_se + s_m;
    ee = (ee >= 0.f) ? ee : NEG_SLOPE * ee;
    float e = has ? ee : (vk ? NEG_INF : -3e38f);

    float m = e;
    #pragma unroll
    for (int off = 16; off; off >>= 1) m = fmaxf(m, __shfl_xor(m, off, 32));
    float p = vk ? expf(e - m) : 0.f;
    float denom = p;
    #pragma unroll
    for (int off = 16; off; off >>= 1) denom += __shfl_xor(denom, off, 32);
    float alpha = p / denom;

    float agg[8];
    #pragma unroll
    for (int j = 0; j < 8; ++j) agg[j] = alpha * msg[j];
    #pragma unroll
    for (int off = 16; off; off >>= 1)
        #pragma unroll
        for (int j = 0; j < 8; ++j) agg[j] += __shfl_xor(agg[j], off, 32);

    if (lane < 8) {
        float o = 0.f;
        #pragma unroll
        for (int i = 0; i < 8; ++i) o += agg[i] * sWg[i * 8 + lane];
        o = (o > 0.f) ? o : (expf(o) - 1.f);
        h2[(size_t)(node + 1) * 8 + lane] = o;
    }
}

// ---------------------------------------------------------------------------
// Kernel 4: readout  out[b,:] = sum_l h[l_scope[b,l], :]
// ---------------------------------------------------------------------------
__global__ void readout_kernel(const float* __restrict__ h,
                               const int* __restrict__ l_scope,
                               float* __restrict__ out, int B, int L) {
    int gid = blockIdx.x * blockDim.x + threadIdx.x;
    int b = gid >> 3;
    int j = gid & 7;
    if (b >= B) return;
    float s = 0.f;
    for (int l = 0; l < L; ++l) {
        int idx = l_scope[(size_t)b * L + l];
        s += h[(size_t)idx * 8 + j];
    }
    out[(size_t)b * 8 + j] = s;
}

// ---------------------------------------------------------------------------
extern "C" void kernel_launch(void* const* d_in, const int* in_sizes, int n_in,
                              void* d_out, int out_size, void* d_ws, size_t ws_size,
                              hipStream_t stream) {
    const float* tf      = (const float*)d_in[0];
    const float* fdg     = (const float*)d_in[1];
    const float* rij     = (const float*)d_in[2];
    const int* b_scope   = (const int*)d_in[3];
    const int* start_env = (const int*)d_in[4];
    const int* l_scope   = (const int*)d_in[5];
    const int* edge_src  = (const int*)d_in[6];
    const float* W_emb   = (const float*)d_in[7];
    const float* b_emb   = (const float*)d_in[8];
    const float* W_dist  = (const float*)d_in[9];
    const float* b_dist  = (const float*)d_in[10];
    const float* W_gat   = (const float*)d_in[11];
    const float* a_src   = (const float*)d_in[12];
    const float* a_dst   = (const float*)d_in[13];
    float* out = (float*)d_out;

    const int N = in_sizes[0] / 8;          // 204800
    const int E = in_sizes[1] / 8;          // 6144000
    const int K = in_sizes[3] / N;          // 30
    const int L = 50;
    const int B = in_sizes[5] / L;          // 4096

    // workspace layout
    size_t rec_f   = (size_t)E * 16;                    // 64 B records
    size_t need    = (rec_f + 2 * (size_t)(N + 1) * 8 + 2 * (size_t)(N + 1)
                      + (size_t)N * K) * 4;
    bool use_rec   = (ws_size >= need);

    float* base = (float*)d_ws;
    float* rec  = base;
    size_t off  = use_rec ? rec_f : 0;
    float* h_a  = base + off;  off += (size_t)(N + 1) * 8;
    float* h_b  = base + off;  off += (size_t)(N + 1) * 8;
    float* t0v  = base + off;  off += (size_t)(N + 1);
    float* t1v  = base + off;  off += (size_t)(N + 1);
    int* src_idx = (int*)(base + off);

    embed_kernel<<<(N + 255) / 256, 256, 0, stream>>>(tf, W_emb, b_emb, W_gat, a_src,
                                                      h_a, h_b, t0v, t1v, N);

    const int gat_blocks = (N + 7) / 8;
    if (use_rec) {
        prep_records<<<(E + 255) / 256, 256, 0, stream>>>(fdg, rij, edge_src,
                                                          W_dist, b_dist, W_gat, a_dst,
                                                          rec, E);
        gat_iter1<true><<<gat_blocks, 256, 0, stream>>>(t0v, h_b, t1v, src_idx,
                                                        b_scope, start_env, rec,
                                                        fdg, rij, edge_src,
                                                        W_dist, b_dist, W_gat, a_src, a_dst,
                                                        N, K);
    } else {
        gat_iter1<false><<<gat_blocks, 256, 0, stream>>>(t0v, h_b, t1v, src_idx,
                                                         b_scope, start_env, rec,
                                                         fdg, rij, edge_src,
                                                         W_dist, b_dist, W_gat, a_src, a_dst,
                                                         N, K);
    }
    gat_iter2<<<gat_blocks, 256, 0, stream>>>(h_b, t1v, h_a, src_idx, start_env,
                                              W_gat, a_dst, N, K);

    readout_kernel<<<(B * 8 + 255) / 256, 256, 0, stream>>>(h_a, l_scope, out, B, L);
}